// Round 5
// baseline (359.839 us; speedup 1.0000x reference)
//
#include <hip/hip_runtime.h>
#include <math.h>

// SegmentedTensorSquareSelfInteraction on MI355X (gfx950)
// N=32768, MUL0=256, MUL1=128, G=64, INV_DIM=448, used gates=576, out=(N,640) fp32
//
// Round 5: full-chain fusion. Per block = 64 nodes; s_all/h/U/o0 live in LDS
// (143 KB of the 160 KB/CU); only weight B-tiles stream per K-step (dbuf,
// 1 barrier/iter). Intermediate HBM traffic: G1 (8.4 MB) only.
// Dispatches: wcast -> fused_main -> fused_o1.
//
// fused_main per block:
//   phase 0: prep   x -> sall_lds[64][456] bf16 (s copy + t0 invariants)
//   phase 1: gemm0  h = silu(sall @ W1 /sq448) -> hbuf[64][520] bf16 (4 col-passes)
//   phase 2: gemm3  gates = h @ W2 /sq448 (K=512, 5 col-passes):
//            cols<448: U = sall*g0 (in-place into sall_lds); 448..575: G1 global
//   phase 3: o0 = U @ Wl0 /sq448 -> o0f (overlays hbuf) fp32 [64][260]
//   phase 4: LayerNorm rows -> out[:, :256]
// fused_o1 per block (64 nodes):
//   stage G1+Wl1 in LDS; build wmat[192][136] bf16 = x_v * g1o; 4-step K-loop
//   (no restaging); dump o1 bf16; RMS per node; out[:, 256:640].

typedef float floatx4 __attribute__((ext_vector_type(4)));
typedef __bf16 bf16x8 __attribute__((ext_vector_type(8)));

__device__ __forceinline__ unsigned short f2bf(float f) {
    union { float f; unsigned u; } v; v.f = f;
    unsigned r = v.u + 0x7FFFu + ((v.u >> 16) & 1u);  // round-to-nearest-even
    return (unsigned short)(r >> 16);
}
__device__ __forceinline__ float bf2f(unsigned short u) {
    union { unsigned u; float f; } v; v.u = ((unsigned)u) << 16; return v.f;
}

// async global->LDS, 16B per lane; LDS dest must be wave-uniform base + lane*16
__device__ __forceinline__ void gl16(const unsigned short* g, unsigned short* l) {
    __builtin_amdgcn_global_load_lds(
        (__attribute__((address_space(1))) void*)(g),
        (__attribute__((address_space(3))) void*)(l), 16, 0, 0);
}

// ---------------------------------------------------------------- weight cast
// W1T [512][448] (rows 448.. zero), W2T [640][512] (col-rows >=576 and k>=448
// zero), Wl0T [256][448], Wl1T [128][128].
__global__ __launch_bounds__(256) void wcast_kernel(
    const float* __restrict__ W1, const float* __restrict__ W2,
    const float* __restrict__ Wl0, const float* __restrict__ Wl1,
    unsigned short* __restrict__ W1T, unsigned short* __restrict__ W2T,
    unsigned short* __restrict__ Wl0T, unsigned short* __restrict__ Wl1T)
{
    int idx = blockIdx.x * 256 + threadIdx.x;
    if (idx < 229376) {                           // W1T: 512 x 448
        int j = idx / 448, k = idx - j * 448;
        W1T[idx] = f2bf((j < 448) ? W1[k * 448 + j] : 0.f);
    } else if (idx < 229376 + 327680) {           // W2T: 640 x 512
        int r = idx - 229376;
        int j = r >> 9, k = r & 511;
        W2T[r] = f2bf((j < 576 && k < 448) ? W2[k * 832 + j] : 0.f);
    } else if (idx < 229376 + 327680 + 114688) {  // Wl0T: 256 x 448
        int r = idx - (229376 + 327680);
        int j = r / 448, k = r - j * 448;
        Wl0T[r] = f2bf(Wl0[k * 256 + j]);
    } else if (idx < 229376 + 327680 + 114688 + 16384) {  // Wl1T: 128 x 128
        int r = idx - (229376 + 327680 + 114688);
        int j = r >> 7, m = r & 127;
        Wl1T[r] = f2bf(Wl1[m * 128 + j]);
    }
}

// ---------------------------------------------------------------- fused main
#define SSTR 456   // sall stride (elems): 912B, 16B-aligned, 2-way banks
#define HSTR 520   // hbuf stride: 1040B aligned; o0f fp32 stride 260 words
__global__ __launch_bounds__(256) void fused_main(
    const float* __restrict__ x,
    const unsigned short* __restrict__ W1T,
    const unsigned short* __restrict__ W2T,
    const unsigned short* __restrict__ Wl0T,
    unsigned short* __restrict__ G1,
    float* __restrict__ out)
{
    __shared__ unsigned short sall[64 * SSTR];      // 58368 B (later holds U)
    __shared__ unsigned short hbuf[64 * HSTR];      // 66560 B (later o0 fp32)
    __shared__ unsigned short Bs[2][128 * 32];      // 16384 B weight staging
    __shared__ float lnS[64][4];
    __shared__ float lnQ[64][4];

    const int tid  = threadIdx.x;
    const int lane = tid & 63;
    const int wid  = tid >> 6;
    const int wm   = (wid >> 1) * 32;   // wave rows: 2 m-subtiles of 16
    const int wn   = (wid & 1) * 64;    // wave cols: 4 n-subtiles of 16
    const int l15  = lane & 15;
    const int quad = lane >> 4;
    const int nb   = blockIdx.x * 64;   // first node of this block

    const float s1 = 0.047245559f;      // 1/sqrt(448)

    // ---------- phase 0: prep -> sall
    for (int i = 0; i < 32; ++i) {
        int idx = i * 256 + tid;                 // 64 nodes x 128 units
        int nl = idx >> 7, r = idx & 127;
        const float* xr = x + (nb + nl) * 640;
        if (r < 64) {
            float4 s = *(const float4*)(xr + 4 * r);
            uint2 p;
            p.x = (unsigned)f2bf(s.x) | ((unsigned)f2bf(s.y) << 16);
            p.y = (unsigned)f2bf(s.z) | ((unsigned)f2bf(s.w) << 16);
            *(uint2*)&sall[nl * SSTR + 4 * r] = p;
        } else {
            int g = r - 64;
            const float2* vg = (const float2*)(xr + 256 + 6 * g);
            float2 p0 = vg[0], p1 = vg[1], p2 = vg[2];
            float ax = p0.x, ay = p0.y, az = p1.x;
            float bx = p1.y, by = p2.x, bz = p2.y;
            float aa = ax*ax + ay*ay + az*az;
            float ab = ax*bx + ay*by + az*bz;
            float bb = bx*bx + by*by + bz*bz;
            const float ISQ3 = 0.57735026918962576f;
            const float SQ2  = 1.41421356237309505f;
            unsigned short* o = &sall[nl * SSTR + 256 + 3 * g];
            o[0] = f2bf(aa * ISQ3);
            o[1] = f2bf(SQ2 * ab * ISQ3);
            o[2] = f2bf(bb * ISQ3);
        }
    }

    const int r0 = tid >> 2;              // staging row 0..63
    const int c8 = (tid & 3) * 8;         // 16B chunk
    unsigned short* BsLo0 = &Bs[0][r0 * 32 + c8];
    unsigned short* BsHi0 = &Bs[0][(r0 + 64) * 32 + c8];
    unsigned short* BsLo1 = &Bs[1][r0 * 32 + c8];
    unsigned short* BsHi1 = &Bs[1][(r0 + 64) * 32 + c8];

    // ---------- phase 1: gemm0 -> hbuf (4 col-passes of 128, K=448)
    for (int cp = 0; cp < 4; ++cp) {
        const unsigned short* Bsrc = W1T + (cp * 128 + r0) * 448 + c8;
        floatx4 acc[2][4] = {};
        __syncthreads();                  // prior Bs users done
        gl16(Bsrc, BsLo0);
        gl16(Bsrc + 64 * 448, BsHi0);
        for (int it = 0; it < 14; ++it) {
            __syncthreads();              // tile `it` DMA drained
            if (it < 13) {                // prefetch it+1
                const unsigned short* s2 = Bsrc + (it + 1) * 32;
                if ((it + 1) & 1) { gl16(s2, BsLo1); gl16(s2 + 64*448, BsHi1); }
                else              { gl16(s2, BsLo0); gl16(s2 + 64*448, BsHi0); }
            }
            const unsigned short* Bb = Bs[it & 1];
            const int k0 = it * 32;
            bf16x8 af[2], bfv[4];
            #pragma unroll
            for (int tm = 0; tm < 2; ++tm)
                af[tm] = *(const bf16x8*)&sall[(wm + tm*16 + l15) * SSTR + k0 + quad*8];
            #pragma unroll
            for (int tn = 0; tn < 4; ++tn)
                bfv[tn] = *(const bf16x8*)&Bb[(wn + tn*16 + l15) * 32 + quad*8];
            #pragma unroll
            for (int tm = 0; tm < 2; ++tm)
                #pragma unroll
                for (int tn = 0; tn < 4; ++tn)
                    acc[tm][tn] = __builtin_amdgcn_mfma_f32_16x16x32_bf16(
                        af[tm], bfv[tn], acc[tm][tn], 0, 0, 0);
        }
        // epilogue: silu -> hbuf (C layout: col=l15, row=quad*4+r; verified)
        #pragma unroll
        for (int tm = 0; tm < 2; ++tm) {
            #pragma unroll
            for (int tn = 0; tn < 4; ++tn) {
                const int col = cp * 128 + wn + tn * 16 + l15;
                #pragma unroll
                for (int r = 0; r < 4; ++r) {
                    const int row = wm + tm * 16 + quad * 4 + r;
                    float v = acc[tm][tn][r] * s1;
                    v = v / (1.f + __expf(-v));
                    hbuf[row * HSTR + col] = f2bf(v);
                }
            }
        }
    }
    __syncthreads();   // h complete (cross-wave cols)

    // ---------- phase 2: gemm3 (K=512, 5 col-passes; gates -> U in-place + G1)
    for (int cp = 0; cp < 5; ++cp) {
        const unsigned short* Bsrc = W2T + (cp * 128 + r0) * 512 + c8;
        floatx4 acc[2][4] = {};
        __syncthreads();
        gl16(Bsrc, BsLo0);
        gl16(Bsrc + 64 * 512, BsHi0);
        for (int it = 0; it < 16; ++it) {
            __syncthreads();
            if (it < 15) {
                const unsigned short* s2 = Bsrc + (it + 1) * 32;
                if ((it + 1) & 1) { gl16(s2, BsLo1); gl16(s2 + 64*512, BsHi1); }
                else              { gl16(s2, BsLo0); gl16(s2 + 64*512, BsHi0); }
            }
            const unsigned short* Bb = Bs[it & 1];
            const int k0 = it * 32;
            bf16x8 af[2], bfv[4];
            #pragma unroll
            for (int tm = 0; tm < 2; ++tm)
                af[tm] = *(const bf16x8*)&hbuf[(wm + tm*16 + l15) * HSTR + k0 + quad*8];
            #pragma unroll
            for (int tn = 0; tn < 4; ++tn)
                bfv[tn] = *(const bf16x8*)&Bb[(wn + tn*16 + l15) * 32 + quad*8];
            #pragma unroll
            for (int tm = 0; tm < 2; ++tm)
                #pragma unroll
                for (int tn = 0; tn < 4; ++tn)
                    acc[tm][tn] = __builtin_amdgcn_mfma_f32_16x16x32_bf16(
                        af[tm], bfv[tn], acc[tm][tn], 0, 0, 0);
        }
        #pragma unroll
        for (int tm = 0; tm < 2; ++tm) {
            #pragma unroll
            for (int tn = 0; tn < 4; ++tn) {
                const int colBase = cp * 128 + wn + tn * 16;
                if (colBase >= 576) continue;
                const int col = colBase + l15;
                #pragma unroll
                for (int r = 0; r < 4; ++r) {
                    const int row = wm + tm * 16 + quad * 4 + r;
                    float v = acc[tm][tn][r] * s1;
                    if (colBase < 448) {          // U = s_all * g0, in place
                        unsigned short* p = &sall[row * SSTR + col];
                        *p = f2bf(bf2f(*p) * v);
                    } else {                      // g1o -> G1 global
                        G1[(nb + row) * 128 + (col - 448)] = f2bf(v);
                    }
                }
            }
        }
    }
    __syncthreads();   // U complete

    // ---------- phase 3: o0 = U @ Wl0 (2 col-passes of 128, K=448) -> o0f
    float* o0f = (float*)hbuf;     // [64][260] fp32, overlays dead hbuf
    for (int cp = 0; cp < 2; ++cp) {
        const unsigned short* Bsrc = Wl0T + (cp * 128 + r0) * 448 + c8;
        floatx4 acc[2][4] = {};
        __syncthreads();
        gl16(Bsrc, BsLo0);
        gl16(Bsrc + 64 * 448, BsHi0);
        for (int it = 0; it < 14; ++it) {
            __syncthreads();
            if (it < 13) {
                const unsigned short* s2 = Bsrc + (it + 1) * 32;
                if ((it + 1) & 1) { gl16(s2, BsLo1); gl16(s2 + 64*448, BsHi1); }
                else              { gl16(s2, BsLo0); gl16(s2 + 64*448, BsHi0); }
            }
            const unsigned short* Bb = Bs[it & 1];
            const int k0 = it * 32;
            bf16x8 af[2], bfv[4];
            #pragma unroll
            for (int tm = 0; tm < 2; ++tm)
                af[tm] = *(const bf16x8*)&sall[(wm + tm*16 + l15) * SSTR + k0 + quad*8];
            #pragma unroll
            for (int tn = 0; tn < 4; ++tn)
                bfv[tn] = *(const bf16x8*)&Bb[(wn + tn*16 + l15) * 32 + quad*8];
            #pragma unroll
            for (int tm = 0; tm < 2; ++tm)
                #pragma unroll
                for (int tn = 0; tn < 4; ++tn)
                    acc[tm][tn] = __builtin_amdgcn_mfma_f32_16x16x32_bf16(
                        af[tm], bfv[tn], acc[tm][tn], 0, 0, 0);
        }
        #pragma unroll
        for (int tm = 0; tm < 2; ++tm)
            #pragma unroll
            for (int tn = 0; tn < 4; ++tn) {
                const int col = cp * 128 + wn + tn * 16 + l15;
                #pragma unroll
                for (int r = 0; r < 4; ++r) {
                    const int row = wm + tm * 16 + quad * 4 + r;
                    o0f[row * 260 + col] = acc[tm][tn][r] * s1;
                }
            }
    }
    __syncthreads();   // o0 complete

    // ---------- phase 4: LayerNorm rows -> out[:, :256]
    {
        const int r = tid >> 2, p = tid & 3;      // 4 threads per row
        const float* rowp = o0f + r * 260 + p * 64;
        float s = 0.f, q = 0.f;
        for (int c = 0; c < 64; ++c) { float v = rowp[c]; s += v; q += v * v; }
        lnS[r][p] = s; lnQ[r][p] = q;
        __syncthreads();
        float ts = lnS[r][0] + lnS[r][1] + lnS[r][2] + lnS[r][3];
        float tq = lnQ[r][0] + lnQ[r][1] + lnQ[r][2] + lnQ[r][3];
        float mu  = ts * (1.f / 256.f);
        float var = tq * (1.f / 256.f) - mu * mu;
        float rln = rsqrtf(var + 1e-6f);
        float* op = out + (nb + r) * 640 + p * 64;
        for (int c = 0; c < 64; c += 4) {
            float4 w;
            w.x = (rowp[c]     - mu) * rln;
            w.y = (rowp[c + 1] - mu) * rln;
            w.z = (rowp[c + 2] - mu) * rln;
            w.w = (rowp[c + 3] - mu) * rln;
            *(float4*)(op + c) = w;
        }
    }
}

// ---------------------------------------------------------------- fused o1
// Per block: 64 nodes -> 192 o1-rows. All-LDS K-loop (no per-iter staging).
#define WSTR 136   // wmat/wl1 stride: 272B, 16B-aligned, 2-way banks
__global__ __launch_bounds__(256) void fused_o1(
    const float* __restrict__ x, const unsigned short* __restrict__ G1,
    const unsigned short* __restrict__ Wl1T, float* __restrict__ out)
{
    __shared__ unsigned short wmat[192 * WSTR];   // 52224 B; later o1 bf16 dump
    __shared__ unsigned short wl1[128 * WSTR];    // 34816 B
    __shared__ unsigned short g1l[64 * 128];      // 16384 B
    __shared__ float qred[64][4];
    __shared__ float rrs[64];

    const int tid  = threadIdx.x;
    const int lane = tid & 63;
    const int wid  = tid >> 6;
    const int l15  = lane & 15;
    const int quad = lane >> 4;
    const int nb   = blockIdx.x * 64;
    const float s2 = 0.088388348f;   // 1/sqrt(128)

    // stage G1 block rows
    for (int i = 0; i < 4; ++i) {
        int flat = i * 256 + tid;                 // 1024 uint4
        int row = flat >> 4, cc = (flat & 15) * 8;
        *(uint4*)&g1l[row * 128 + cc] = *(const uint4*)&G1[(nb + row) * 128 + cc];
    }
    // stage Wl1T
    for (int i = 0; i < 8; ++i) {
        int row = (tid >> 4) + 16 * i, cc = (tid & 15) * 8;
        *(uint4*)&wl1[row * WSTR + cc] = *(const uint4*)&Wl1T[row * 128 + cc];
    }
    __syncthreads();

    // build wmat[(nl*3+i)][m] = x[n, 256+3m+i] * g1[n, m]
    for (int i = 0; i < 24; ++i) {
        int flat = i * 256 + tid;                 // 6144 float4 units
        int nl = flat / 96, w4 = flat - nl * 96;
        float4 v = *(const float4*)&x[(nb + nl) * 640 + 256 + w4 * 4];
        int c = w4 * 4;
        const float* vf = (const float*)&v;
        #pragma unroll
        for (int e = 0; e < 4; ++e) {
            int cc = c + e;
            int m = cc / 3, i2 = cc - 3 * m;
            float g = bf2f(g1l[nl * 128 + m]);
            wmat[(nl * 3 + i2) * WSTR + m] = f2bf(vf[e] * g);
        }
    }
    __syncthreads();

    // K-loop: wave = 48 rows (3 m-subtiles) x 128 cols (8 n-subtiles), K=128
    const int wrow = wid * 48;
    floatx4 acc[3][8] = {};
    for (int k0 = 0; k0 < 128; k0 += 32) {
        bf16x8 af[3], bfv[8];
        #pragma unroll
        for (int tm = 0; tm < 3; ++tm)
            af[tm] = *(const bf16x8*)&wmat[(wrow + tm*16 + l15) * WSTR + k0 + quad*8];
        #pragma unroll
        for (int tn = 0; tn < 8; ++tn)
            bfv[tn] = *(const bf16x8*)&wl1[(tn*16 + l15) * WSTR + k0 + quad*8];
        #pragma unroll
        for (int tm = 0; tm < 3; ++tm)
            #pragma unroll
            for (int tn = 0; tn < 8; ++tn)
                acc[tm][tn] = __builtin_amdgcn_mfma_f32_16x16x32_bf16(
                    af[tm], bfv[tn], acc[tm][tn], 0, 0, 0);
    }
    __syncthreads();   // all waves done reading wmat

    // dump o1 bf16 into wmat region (C layout verified)
    #pragma unroll
    for (int tm = 0; tm < 3; ++tm)
        #pragma unroll
        for (int tn = 0; tn < 8; ++tn) {
            const int col = tn * 16 + l15;
            #pragma unroll
            for (int r = 0; r < 4; ++r) {
                const int row = wrow + tm * 16 + quad * 4 + r;
                wmat[row * WSTR + col] = f2bf(acc[tm][tn][r] * s2);
            }
        }
    __syncthreads();

    // q per node (3 rows x 128 cols each)
    {
        int nd = tid >> 2, p = tid & 3;
        float q = 0.f;
        for (int i2 = 0; i2 < 3; ++i2) {
            const unsigned short* rp = &wmat[(nd * 3 + i2) * WSTR + p * 32];
            for (int c = 0; c < 32; ++c) { float v = bf2f(rp[c]); q += v * v; }
        }
        qred[nd][p] = q;
    }
    __syncthreads();
    if (tid < 64)
        rrs[tid] = rsqrtf((qred[tid][0] + qred[tid][1] + qred[tid][2] + qred[tid][3])
                          * (1.f / 384.f) + 1e-6f);
    __syncthreads();

    // write out[:, 256+j], j = 3k+i2 -> o1[(3nd+i2)][k] * rrms
    for (int i = 0; i < 96; ++i) {
        int flat = i * 256 + tid;                 // 24576
        int nd = flat / 384, j = flat - nd * 384;
        int k = j / 3, i2 = j - 3 * k;
        out[(nb + nd) * 640 + 256 + j] = bf2f(wmat[(nd * 3 + i2) * WSTR + k]) * rrs[nd];
    }
}

// ---------------------------------------------------------------- launch
extern "C" void kernel_launch(void* const* d_in, const int* in_sizes, int n_in,
                              void* d_out, int out_size, void* d_ws, size_t ws_size,
                              hipStream_t stream) {
    const float* x   = (const float*)d_in[0];
    const float* W1  = (const float*)d_in[1];
    const float* W2  = (const float*)d_in[2];
    const float* Wl0 = (const float*)d_in[3];
    const float* Wl1 = (const float*)d_in[4];
    float* out = (float*)d_out;
    char* ws = (char*)d_ws;

    unsigned short* W1T  = (unsigned short*)(ws + 0);         //   458,752 B
    unsigned short* W2T  = (unsigned short*)(ws + 458752);    //   655,360 B
    unsigned short* Wl0T = (unsigned short*)(ws + 1114112);   //   229,376 B
    unsigned short* Wl1T = (unsigned short*)(ws + 1343488);   //    32,768 B
    unsigned short* G1   = (unsigned short*)(ws + 1376256);   // 8,388,608 B
    // peak ws: 9,764,864 bytes

    wcast_kernel<<<dim3(2688), dim3(256), 0, stream>>>(W1, W2, Wl0, Wl1,
                                                       W1T, W2T, Wl0T, Wl1T);
    fused_main<<<dim3(512), dim3(256), 0, stream>>>(x, W1T, W2T, Wl0T, G1, out);
    fused_o1<<<dim3(512), dim3(256), 0, stream>>>(x, G1, Wl1T, out);
}